// Round 7
// baseline (99.364 us; speedup 1.0000x reference)
//
#include <hip/hip_runtime.h>

typedef _Float16 h2 __attribute__((ext_vector_type(2)));
typedef unsigned int u32;

// Workspace layout (bytes).
#define OFF_W2H  0xA0000u   // half2[128]   W2 h-pair packed
#define OFF_A2   0x100000u  // half2 [1024 row][128 hh]  pre_x      (row-major)
#define OFF_C2   0x180000u  // half2 [1024 row][128 hh]  pre_y + b1 (row-major)

__device__ __forceinline__ u32 pack2(float a, float b) {
  h2 v; v.x = (_Float16)a; v.y = (_Float16)b;
  return __builtin_bit_cast(u32, v);
}
__device__ __forceinline__ h2 as_h2(u32 u) { return __builtin_bit_cast(h2, u); }

__device__ __forceinline__ h2 cvt2(float a, float b) {
#if __has_builtin(__builtin_amdgcn_cvt_pkrtz)
  return __builtin_bit_cast(h2, __builtin_amdgcn_cvt_pkrtz(a, b));  // v_cvt_pkrtz_f16_f32
#else
  h2 v; v.x = (_Float16)a; v.y = (_Float16)b; return v;
#endif
}
__device__ __forceinline__ float fdot2(h2 a, h2 b, float c) {
#if __has_builtin(__builtin_amdgcn_fdot2)
  return __builtin_amdgcn_fdot2(a, b, c, false);
#else
  return (float)a.x * (float)b.x + (float)a.y * (float)b.y + c;
#endif
}
__device__ __forceinline__ h2 relu2(h2 t) {
  h2 z; z.x = (_Float16)0.0f; z.y = (_Float16)0.0f;
  return __builtin_elementwise_max(t, z);       // v_pk_max_f16
}

// K1: pre_x -> A2, pre_y + b1 -> C2, straight from raw fp32 inputs
// (in-register cvt_pkrtz). Block 256: W2 pack + out init.
// Output (u32 = half2 of h-pair): idx = row*128 + hh  (row-major).
__global__ __launch_bounds__(256) void k1_pre(const float* __restrict__ x,
                                              const float* __restrict__ y,
                                              const float* __restrict__ W1,
                                              const float* __restrict__ b1,
                                              const float* __restrict__ W2,
                                              u32* __restrict__ wsu,
                                              float* __restrict__ out) {
  const int b = blockIdx.x, tid = threadIdx.x;
  if (b == 256) {                               // W2 h-pair pack + accumulator init
    if (tid < 128) wsu[(OFF_W2H >> 2) + tid] = pack2(W2[2 * tid], W2[2 * tid + 1]);
    if (tid == 128) out[0] = 0.0f;              // d_out is poisoned by harness
    return;
  }
  const int mat = b >> 7;                       // 0: x->A2, 1: y->C2
  const int idx = b & 127, ht = idx & 7, rt = idx >> 3;  // 16 hh x 64 rows per block
  const int tx = tid & 15, ty = tid >> 4;       // hh lane, row group
  const int h0 = ht * 32 + tx * 2;              // this thread's two h columns
  const int r0 = rt * 64 + ty * 4;              // this thread's four rows
  const float* src = (mat ? y : x) + r0 * 128;
  const float* w1p = W1 + (mat ? 128 * 256 : 0) + h0;
  u32* dst = wsu + ((mat ? OFF_C2 : OFF_A2) >> 2) + ht * 16 + tx;

  float acc0[4], acc1[4];
  float bx = 0.0f, by = 0.0f;
  if (mat) { const float2 bv = *(const float2*)(b1 + h0); bx = bv.x; by = bv.y; }
#pragma unroll
  for (int i = 0; i < 4; ++i) { acc0[i] = bx; acc1[i] = by; }

#pragma unroll 4
  for (int kk = 0; kk < 64; ++kk) {
    const float2 wA = *(const float2*)(w1p + (2 * kk) * 256);       // coalesced
    const float2 wB = *(const float2*)(w1p + (2 * kk + 1) * 256);
    const h2 w0 = cvt2(wA.x, wB.x);
    const h2 w1h = cvt2(wA.y, wB.y);
#pragma unroll
    for (int i = 0; i < 4; ++i) {               // x[r, 2kk:2kk+2]: 16-lane broadcast
      const float2 xv = *(const float2*)(src + i * 128 + 2 * kk);
      const h2 xh = cvt2(xv.x, xv.y);
      acc0[i] = fdot2(xh, w0, acc0[i]);
      acc1[i] = fdot2(xh, w1h, acc1[i]);
    }
  }
#pragma unroll
  for (int i = 0; i < 4; ++i) {
    const int R = r0 + i;
    dst[R * 128] = pack2(acc0[i], acc1[i]);
  }
}

// K2: main N^2 kernel. 256 blocks of 64x64 rows; 4x4 rows/thread (16 acc).
// A-slab (32KB) in LDS, layout [quad g][perm(row)] with perm(row) =
// (row>>2)|((row&3)<<4): inner reads are ds_read_b128 with IMMEDIATE offset
// g*1024, banks spread 8-wide across tx (2-way alias = free). C-operand read
// straight from global (quarter-wave broadcast, L1-resident 32KB/block) --
// takes C off the LDS pipe entirely: LDS 192 cyc/CU/group vs VALU 416/SIMD,
// 2x slack. W2 via wave-uniform load (s_load). VALU floor ~5.5us.
__global__ __launch_bounds__(256) void k2_main(const u32* __restrict__ wsu,
                                               const float* __restrict__ B2,
                                               float* __restrict__ out) {
  const int bi = blockIdx.x >> 4, bj = blockIdx.x & 15;
  const int tid = threadIdx.x;
  const int tx = tid & 15, ty = tid >> 4;       // j-group, i-group (4 rows each)

  __shared__ uint4 sA4[32 * 64];                // [quad][perm(row)]  32KB
  __shared__ float sred[4];

  {                                             // stage A: lane=row, 8 quads/thread
    const u32* gA = wsu + (OFF_A2 >> 2) + bj * 8192;
    const int row = tid & 63, qb = (tid >> 6) * 8;
    const int pr = (row >> 2) | ((row & 3) << 4);
#pragma unroll
    for (int m = 0; m < 8; ++m) {
      const int q = qb + m;
      sA4[q * 64 + pr] = *(const uint4*)(gA + row * 128 + q * 4);
    }
  }
  __syncthreads();

  const uint4* pA = sA4 + tx;                   // + r*16 + g*64 (imm offsets)
  const uint4* gC = (const uint4*)(wsu + (OFF_C2 >> 2)) + (bi * 64 + ty * 4) * 32;
  const uint4* pW = (const uint4*)(wsu + (OFF_W2H >> 2));  // uniform

  float acc[16];
#pragma unroll
  for (int p = 0; p < 16; ++p) acc[p] = 0.0f;

#pragma unroll 4
  for (int g = 0; g < 32; ++g) {                // 4 hh per step
    const uint4 av0 = pA[g * 64 + 0];           // A rows 4tx+0..3 (perm'd)
    const uint4 av1 = pA[g * 64 + 16];
    const uint4 av2 = pA[g * 64 + 32];
    const uint4 av3 = pA[g * 64 + 48];
    const uint4 cv0 = gC[0 * 32 + g];           // C rows 4ty+0..3 (broadcast)
    const uint4 cv1 = gC[1 * 32 + g];
    const uint4 cv2 = gC[2 * 32 + g];
    const uint4 cv3 = gC[3 * 32 + g];
    const uint4 wv = pW[g];
    const u32 ww[4] = {wv.x, wv.y, wv.z, wv.w};
    const u32 aa[4][4] = {{av0.x, av0.y, av0.z, av0.w},
                          {av1.x, av1.y, av1.z, av1.w},
                          {av2.x, av2.y, av2.z, av2.w},
                          {av3.x, av3.y, av3.z, av3.w}};
    const u32 cc[4][4] = {{cv0.x, cv0.y, cv0.z, cv0.w},
                          {cv1.x, cv1.y, cv1.z, cv1.w},
                          {cv2.x, cv2.y, cv2.z, cv2.w},
                          {cv3.x, cv3.y, cv3.z, cv3.w}};
#pragma unroll
    for (int m = 0; m < 4; ++m) {               // all indices compile-time
      const h2 w = as_h2(ww[m]);
#pragma unroll
      for (int ii = 0; ii < 4; ++ii) {
        const h2 ci = as_h2(cc[ii][m]);
#pragma unroll
        for (int jj = 0; jj < 4; ++jj) {
          acc[ii * 4 + jj] = fdot2(relu2(as_h2(aa[jj][m]) + ci), w, acc[ii * 4 + jj]);
        }
      }
    }
  }

  // result = (1/n) sum_i (T1_ii + 1) - (1/n^2) sum_ij exp(T1_ij),
  // T1_ij = d_ij + b2 - 1.  acc[] holds d_ij.
  const float b2 = B2[0];
  float val = 0.0f;
#pragma unroll
  for (int p = 0; p < 16; ++p) val += __expf(acc[p] + (b2 - 1.0f));
  val *= -1.0f / 1048576.0f;
  if (bi == bj && tx == ty) {                   // diag: local i==j -> acc[c*5]
    float d = 0.0f;
#pragma unroll
    for (int c = 0; c < 4; ++c) d += acc[c * 5];
    val += (d + 4.0f * b2) * (1.0f / 1024.0f);
  }
#pragma unroll
  for (int off = 32; off > 0; off >>= 1) val += __shfl_down(val, off, 64);
  if ((tid & 63) == 0) sred[tid >> 6] = val;
  __syncthreads();
  if (tid == 0) atomicAdd(out, sred[0] + sred[1] + sred[2] + sred[3]);
}

extern "C" void kernel_launch(void* const* d_in, const int* in_sizes, int n_in,
                              void* d_out, int out_size, void* d_ws, size_t ws_size,
                              hipStream_t stream) {
  const float* x  = (const float*)d_in[0];
  const float* y  = (const float*)d_in[1];
  const float* W1 = (const float*)d_in[2];
  const float* b1 = (const float*)d_in[3];
  const float* W2 = (const float*)d_in[4];
  const float* b2 = (const float*)d_in[5];
  u32* wsu = (u32*)d_ws;

  hipLaunchKernelGGL(k1_pre, dim3(257), dim3(256), 0, stream, x, y, W1, b1, W2,
                     wsu, (float*)d_out);
  hipLaunchKernelGGL(k2_main, dim3(256), dim3(256), 0, stream, wsu, b2,
                     (float*)d_out);
}

// Round 8
// 94.854 us; speedup vs baseline: 1.0475x; 1.0475x over previous
//
#include <hip/hip_runtime.h>

typedef _Float16 h2 __attribute__((ext_vector_type(2)));
typedef unsigned int u32;

// Workspace layout (bytes).
#define OFF_W2H  0xA0000u   // half2[128]   W2 h-pair packed
#define OFF_A2   0x100000u  // half2 [1024 row][128 hh]  pre_x      (row-major)
#define OFF_C2   0x180000u  // half2 [1024 row][128 hh]  pre_y + b1 (row-major)

__device__ __forceinline__ u32 pack2(float a, float b) {
  h2 v; v.x = (_Float16)a; v.y = (_Float16)b;
  return __builtin_bit_cast(u32, v);
}
__device__ __forceinline__ h2 as_h2(u32 u) { return __builtin_bit_cast(h2, u); }

__device__ __forceinline__ h2 cvt2(float a, float b) {
#if __has_builtin(__builtin_amdgcn_cvt_pkrtz)
  return __builtin_bit_cast(h2, __builtin_amdgcn_cvt_pkrtz(a, b));  // v_cvt_pkrtz_f16_f32
#else
  h2 v; v.x = (_Float16)a; v.y = (_Float16)b; return v;
#endif
}
__device__ __forceinline__ float fdot2(h2 a, h2 b, float c) {
#if __has_builtin(__builtin_amdgcn_fdot2)
  return __builtin_amdgcn_fdot2(a, b, c, false);
#else
  return (float)a.x * (float)b.x + (float)a.y * (float)b.y + c;
#endif
}
__device__ __forceinline__ h2 relu2(h2 t) {
  h2 z; z.x = (_Float16)0.0f; z.y = (_Float16)0.0f;
  return __builtin_elementwise_max(t, z);       // v_pk_max_f16
}

// K1: pre_x -> A2, pre_y + b1 -> C2, straight from raw fp32 inputs
// (in-register cvt_pkrtz). Block 256: W2 pack + out init.
// Output (u32 = half2 of h-pair): idx = row*128 + hh  (row-major).
__global__ __launch_bounds__(256) void k1_pre(const float* __restrict__ x,
                                              const float* __restrict__ y,
                                              const float* __restrict__ W1,
                                              const float* __restrict__ b1,
                                              const float* __restrict__ W2,
                                              u32* __restrict__ wsu,
                                              float* __restrict__ out) {
  const int b = blockIdx.x, tid = threadIdx.x;
  if (b == 256) {                               // W2 h-pair pack + accumulator init
    if (tid < 128) wsu[(OFF_W2H >> 2) + tid] = pack2(W2[2 * tid], W2[2 * tid + 1]);
    if (tid == 128) out[0] = 0.0f;              // d_out is poisoned by harness
    return;
  }
  const int mat = b >> 7;                       // 0: x->A2, 1: y->C2
  const int idx = b & 127, ht = idx & 7, rt = idx >> 3;  // 16 hh x 64 rows per block
  const int tx = tid & 15, ty = tid >> 4;       // hh lane, row group
  const int h0 = ht * 32 + tx * 2;              // this thread's two h columns
  const int r0 = rt * 64 + ty * 4;              // this thread's four rows
  const float* src = (mat ? y : x) + r0 * 128;
  const float* w1p = W1 + (mat ? 128 * 256 : 0) + h0;
  u32* dst = wsu + ((mat ? OFF_C2 : OFF_A2) >> 2) + ht * 16 + tx;

  float acc0[4], acc1[4];
  float bx = 0.0f, by = 0.0f;
  if (mat) { const float2 bv = *(const float2*)(b1 + h0); bx = bv.x; by = bv.y; }
#pragma unroll
  for (int i = 0; i < 4; ++i) { acc0[i] = bx; acc1[i] = by; }

#pragma unroll 4
  for (int kk = 0; kk < 64; ++kk) {
    const float2 wA = *(const float2*)(w1p + (2 * kk) * 256);       // coalesced
    const float2 wB = *(const float2*)(w1p + (2 * kk + 1) * 256);
    const h2 w0 = cvt2(wA.x, wB.x);
    const h2 w1h = cvt2(wA.y, wB.y);
#pragma unroll
    for (int i = 0; i < 4; ++i) {               // x[r, 2kk:2kk+2]: 16-lane broadcast
      const float2 xv = *(const float2*)(src + i * 128 + 2 * kk);
      const h2 xh = cvt2(xv.x, xv.y);
      acc0[i] = fdot2(xh, w0, acc0[i]);
      acc1[i] = fdot2(xh, w1h, acc1[i]);
    }
  }
#pragma unroll
  for (int i = 0; i < 4; ++i) {
    const int R = r0 + i;
    dst[R * 128] = pack2(acc0[i], acc1[i]);
  }
}

// K2: main N^2 kernel. 1024 blocks of 32x32 rows, 2x2 rows/thread, 4 blocks/CU
// (4 waves/SIMD TLP -- R3's occupancy, which beat every 1-wave/SIMD design).
// Per 4-hh group/wave: 2 ds_read_b128 (A, imm-offset perm layout) + 2 global
// broadcast (C, 16KB L1-resident) + 1 s_load (W2). LDS/CU/group = 16w*2*12 =
// 384 cyc == VALU 4w*96 = 384 cyc/SIMD: balanced WITH latency tolerance.
__global__ __launch_bounds__(256) void k2_main(const u32* __restrict__ wsu,
                                               const float* __restrict__ B2,
                                               float* __restrict__ out) {
  const int bi = blockIdx.x >> 5, bj = blockIdx.x & 31;
  const int tid = threadIdx.x;
  const int tx = tid & 15, ty = tid >> 4;       // j-pair, i-pair

  __shared__ uint4 sA4[32 * 32];                // [quad g][perm(row)], 16KB
  __shared__ float sred[4];

  {                                             // stage A: coalesced 1KB/wave-instr
    const u32* gA = wsu + (OFF_A2 >> 2) + bj * 4096;
    const int row = tid >> 3, t8 = tid & 7;
    const int pr = (row >> 1) | ((row & 1) << 4);
#pragma unroll
    for (int m = 0; m < 4; ++m) {
      const int q = t8 + 8 * m;
      sA4[q * 32 + pr] = *(const uint4*)(gA + row * 128 + q * 4);
    }
  }
  __syncthreads();

  const uint4* pA = sA4 + tx;                   // rows 2tx (+0), 2tx+1 (+16)
  const uint4* gC = (const uint4*)(wsu + (OFF_C2 >> 2)) + (bi * 32 + ty * 2) * 32;
  const uint4* pW = (const uint4*)(wsu + (OFF_W2H >> 2));  // uniform -> s_load

  float acc[4] = {0.0f, 0.0f, 0.0f, 0.0f};

#pragma unroll 4
  for (int g = 0; g < 32; ++g) {                // 4 hh per step
    const uint4 av0 = pA[g * 32];               // A row 2tx   (ds, imm offset)
    const uint4 av1 = pA[g * 32 + 16];          // A row 2tx+1
    const uint4 cv0 = gC[g];                    // C row 2ty   (global broadcast)
    const uint4 cv1 = gC[32 + g];               // C row 2ty+1
    const uint4 wv = pW[g];
    const u32 aa0[4] = {av0.x, av0.y, av0.z, av0.w};
    const u32 aa1[4] = {av1.x, av1.y, av1.z, av1.w};
    const u32 cc0[4] = {cv0.x, cv0.y, cv0.z, cv0.w};
    const u32 cc1[4] = {cv1.x, cv1.y, cv1.z, cv1.w};
    const u32 ww[4] = {wv.x, wv.y, wv.z, wv.w};
#pragma unroll
    for (int m = 0; m < 4; ++m) {               // all indices compile-time
      const h2 w = as_h2(ww[m]);
      const h2 A0 = as_h2(aa0[m]), A1 = as_h2(aa1[m]);
      const h2 C0 = as_h2(cc0[m]), C1 = as_h2(cc1[m]);
      acc[0] = fdot2(relu2(A0 + C0), w, acc[0]);
      acc[1] = fdot2(relu2(A1 + C0), w, acc[1]);
      acc[2] = fdot2(relu2(A0 + C1), w, acc[2]);
      acc[3] = fdot2(relu2(A1 + C1), w, acc[3]);
    }
  }

  // result = (1/n) sum_i (T1_ii + 1) - (1/n^2) sum_ij exp(T1_ij),
  // T1_ij = d_ij + b2 - 1.  acc[] holds d_ij.
  const float b2 = B2[0];
  float val = 0.0f;
#pragma unroll
  for (int p = 0; p < 4; ++p) val += __expf(acc[p] + (b2 - 1.0f));
  val *= -1.0f / 1048576.0f;
  if (bi == bj && tx == ty)                     // diag: acc[0] (2tx==2ty), acc[3]
    val += (acc[0] + acc[3] + 2.0f * b2) * (1.0f / 1024.0f);
#pragma unroll
  for (int off = 32; off > 0; off >>= 1) val += __shfl_down(val, off, 64);
  if ((tid & 63) == 0) sred[tid >> 6] = val;
  __syncthreads();
  if (tid == 0) atomicAdd(out, sred[0] + sred[1] + sred[2] + sred[3]);
}

extern "C" void kernel_launch(void* const* d_in, const int* in_sizes, int n_in,
                              void* d_out, int out_size, void* d_ws, size_t ws_size,
                              hipStream_t stream) {
  const float* x  = (const float*)d_in[0];
  const float* y  = (const float*)d_in[1];
  const float* W1 = (const float*)d_in[2];
  const float* b1 = (const float*)d_in[3];
  const float* W2 = (const float*)d_in[4];
  const float* b2 = (const float*)d_in[5];
  u32* wsu = (u32*)d_ws;

  hipLaunchKernelGGL(k1_pre, dim3(257), dim3(256), 0, stream, x, y, W1, b1, W2,
                     wsu, (float*)d_out);
  hipLaunchKernelGGL(k2_main, dim3(1024), dim3(256), 0, stream, wsu, b2,
                     (float*)d_out);
}